// Round 1
// baseline (788.045 us; speedup 1.0000x reference)
//
#include <hip/hip_runtime.h>
#include <stdint.h>

#define K_   367
#define P_   217
#define Q_   721
#define QC   217
#define CPQ  (217*217)              // 47089 corner positions
#define PQ_  (217*721)              // 156457 full positions
#define TOT  ((long long)K_*PQ_)    // 57,419,719 (k,p,q) entries

// Pack (i0,i1,w) -> u32: low 16 bits = i0*217+i1 (<47089), high 16 bits = round(w*65536)
__global__ __launch_bounds__(256) void pack_kernel(
    const int2* __restrict__ ind, const float* __restrict__ w,
    uint32_t* __restrict__ packed)
{
    long long i = (long long)blockIdx.x * blockDim.x + threadIdx.x;
    if (i >= TOT) return;
    int2 ij = ind[i];
    float wv = w[i];
    uint32_t wq = (uint32_t)(wv * 65536.0f + 0.5f);
    if (wq > 65535u) wq = 65535u;
    packed[i] = (uint32_t)(ij.x * QC + ij.y) | (wq << 16);
}

// Copy 217x217 corner of inputs [2,256,256,1] into interleaved float2 buffer
__global__ __launch_bounds__(256) void copy_kernel(
    const float* __restrict__ inp, float2* __restrict__ y0)
{
    int o = blockIdx.x * blockDim.x + threadIdx.x;
    if (o >= CPQ) return;
    int p = o / QC, q = o - p * QC;
    y0[o] = make_float2(inp[p * 256 + q], inp[65536 + p * 256 + q]);
}

// One iteration. FULL=false: compute only corner outputs (q<217), write interleaved float2.
// FULL=true: compute all 721 columns, write d_out planes [2][PQ_].
// k is split across blockIdx.y chunks; partial sums combined with atomicAdd.
template<bool FULL, bool PACKED>
__global__ __launch_bounds__(256) void iter_kernel(
    const uint32_t* __restrict__ packed,
    const int2* __restrict__ ind, const float* __restrict__ w1,
    const float2* __restrict__ yin,
    float* __restrict__ outp,
    const float* __restrict__ lam_p)
{
    const int nout = FULL ? PQ_ : CPQ;
    int o = blockIdx.x * blockDim.x + threadIdx.x;
    if (o >= nout) return;
    int p, q;
    if (FULL) { p = o / Q_; q = o - p * Q_; }
    else      { p = o / QC; q = o - p * QC; }
    int KS = gridDim.y;
    int klen = (K_ + KS - 1) / KS;
    int k0 = blockIdx.y * klen;
    int k1 = min(K_, k0 + klen);
    long long base = (long long)(k0 * P_ + p) * Q_ + q;
    float acc0 = 0.f, acc1 = 0.f;
    if (PACKED) {
        const uint32_t* pp = packed + base;
        #pragma unroll 8
        for (int k = k0; k < k1; ++k, pp += PQ_) {
            uint32_t v = *pp;                 // coalesced stream
            float2 g = yin[v & 0xFFFFu];      // L2-resident gather (both batches)
            float wv = (float)(v >> 16);
            acc0 = fmaf(wv, g.x, acc0);
            acc1 = fmaf(wv, g.y, acc1);
        }
        float ls = *lam_p * (1.0f / 65536.0f);
        acc0 *= ls; acc1 *= ls;
    } else {
        const int2*  ip = ind + base;
        const float* wp = w1 + base;
        #pragma unroll 4
        for (int k = k0; k < k1; ++k, ip += PQ_, wp += PQ_) {
            int2 ij = *ip;
            float wv = *wp;
            float2 g = yin[ij.x * QC + ij.y];
            acc0 = fmaf(wv, g.x, acc0);
            acc1 = fmaf(wv, g.y, acc1);
        }
        float ls = *lam_p;
        acc0 *= ls; acc1 *= ls;
    }
    if (FULL) {
        atomicAdd(&outp[o], acc0);
        atomicAdd(&outp[PQ_ + o], acc1);
    } else {
        atomicAdd(&outp[2 * o], acc0);
        atomicAdd(&outp[2 * o + 1], acc1);
    }
}

extern "C" void kernel_launch(void* const* d_in, const int* in_sizes, int n_in,
                              void* d_out, int out_size, void* d_ws, size_t ws_size,
                              hipStream_t stream)
{
    const float* inp = (const float*)d_in[0];
    const int2*  ind = (const int2*)d_in[1];
    const float* w1  = (const float*)d_in[2];
    const float* lam = (const float*)d_in[3];
    float* out = (float*)d_out;

    size_t packed_bytes = (((size_t)TOT * 4) + 255) & ~(size_t)255;
    size_t ybytes = (size_t)CPQ * sizeof(float2);
    bool use_packed = ws_size >= packed_bytes + 2 * ybytes;

    uint8_t* ws = (uint8_t*)d_ws;
    uint32_t* packed = nullptr;
    float2 *y0, *y1;
    if (use_packed) {
        packed = (uint32_t*)ws;
        y0 = (float2*)(ws + packed_bytes);
        y1 = (float2*)(ws + packed_bytes + ybytes);
    } else {
        y0 = (float2*)ws;
        y1 = (float2*)(ws + ybytes);
    }

    if (use_packed) {
        unsigned nb = (unsigned)((TOT + 255) / 256);
        pack_kernel<<<dim3(nb), 256, 0, stream>>>(ind, w1, packed);
    }
    copy_kernel<<<(CPQ + 255) / 256, 256, 0, stream>>>(inp, y0);

    float2* yin = y0; float2* yout = y1;
    const int KS_C = 8, KS_F = 4;
    for (int it = 0; it < 4; ++it) {
        hipMemsetAsync(yout, 0, ybytes, stream);
        dim3 g((CPQ + 255) / 256, KS_C);
        if (use_packed)
            iter_kernel<false, true><<<g, 256, 0, stream>>>(packed, nullptr, nullptr, yin, (float*)yout, lam);
        else
            iter_kernel<false, false><<<g, 256, 0, stream>>>(nullptr, ind, w1, yin, (float*)yout, lam);
        float2* t = yin; yin = yout; yout = t;
    }
    hipMemsetAsync(out, 0, (size_t)PQ_ * 2 * sizeof(float), stream);
    dim3 g((PQ_ + 255) / 256, KS_F);
    if (use_packed)
        iter_kernel<true, true><<<g, 256, 0, stream>>>(packed, nullptr, nullptr, yin, out, lam);
    else
        iter_kernel<true, false><<<g, 256, 0, stream>>>(nullptr, ind, w1, yin, out, lam);
}

// Round 2
// 493.927 us; speedup vs baseline: 1.5955x; 1.5955x over previous
//
#include <hip/hip_runtime.h>
#include <stdint.h>

#define K_   367
#define P_   217
#define Q_   721
#define QC   217
#define CPQ  (QC*QC)                // 47089 corner positions
#define YSTR 47104                  // padded plane stride (floats), 16B aligned
#define PQ_  (P_*Q_)                // 156457 full positions
#define TOT  ((long long)K_*PQ_)    // 57,419,719 entries
#define LDSN 40960                  // floats staged in LDS (160 KB) -> covers 87% of indices

// Pack (i0,i1,w) -> u32: low 16 = i0*217+i1 (<47089), high 16 = round(w*65536)
__global__ __launch_bounds__(256) void pack_kernel(
    const int2* __restrict__ ind, const float* __restrict__ w,
    uint32_t* __restrict__ packed)
{
    long long i = (long long)blockIdx.x * blockDim.x + threadIdx.x;
    if (i >= TOT) return;
    int2 ij = ind[i];
    float wv = w[i];
    uint32_t wq = (uint32_t)(wv * 65536.0f + 0.5f);
    if (wq > 65535u) wq = 65535u;
    packed[i] = (uint32_t)(ij.x * QC + ij.y) | (wq << 16);
}

// Copy 217x217 corner of inputs [2,256,256,1] into two fp32 planes (stride YSTR)
__global__ __launch_bounds__(256) void copy_kernel(
    const float* __restrict__ inp, float* __restrict__ y0)
{
    int o = blockIdx.x * blockDim.x + threadIdx.x;
    if (o >= CPQ) return;
    int p = o / QC, q = o - p * QC;
    y0[o]        = inp[p * 256 + q];
    y0[YSTR + o] = inp[65536 + p * 256 + q];
}

// One iteration, one batch per blockIdx.z. Persistent blocks: fill LDS with the
// first LDSN floats of this batch's y plane once, then loop over (o-chunk, k-chunk)
// units. Gathers: 87% from LDS, 13% from the hot 24.5KB global tail (L1-resident).
// FULL=false: corner outputs (stride YSTR). FULL=true: all PQ_ outputs (stride PQ_).
template<bool FULL, bool PACKED>
__global__ __launch_bounds__(1024) void iter_lds(
    const uint32_t* __restrict__ packed,
    const int2* __restrict__ ind, const float* __restrict__ w1,
    const float* __restrict__ yin,    // 2 planes, stride YSTR
    float* __restrict__ yout,         // 2 planes, stride (FULL ? PQ_ : YSTR)
    const float* __restrict__ lam_p,
    int KS)
{
    __shared__ float ylds[LDSN];
    const int b = blockIdx.z;
    const float* __restrict__ yplane = yin + (size_t)b * YSTR;

    // cooperative LDS fill (float4, coalesced)
    {
        const float4* s4 = (const float4*)yplane;
        float4* d4 = (float4*)ylds;
        for (int i = threadIdx.x; i < LDSN / 4; i += 1024) d4[i] = s4[i];
    }
    __syncthreads();

    const int nout = FULL ? PQ_ : CPQ;
    const int gx = (nout + 1023) / 1024;
    const int nunits = gx * KS;
    const int klen = (K_ + KS - 1) / KS;
    const float ls = *lam_p * (PACKED ? (1.0f / 65536.0f) : 1.0f);
    const int ostr = FULL ? PQ_ : YSTR;

    for (int unit = blockIdx.x; unit < nunits; unit += gridDim.x) {
        int ob = unit % gx;
        int kc = unit / gx;
        int o = ob * 1024 + threadIdx.x;
        if (o >= nout) continue;
        int soff;
        if (FULL) soff = o;
        else { int p = o / QC; soff = p * Q_ + (o - p * QC); }
        int k0 = kc * klen;
        int k1 = min(K_, k0 + klen);
        float acc = 0.f;
        if (PACKED) {
            const uint32_t* pp = packed + (long long)k0 * PQ_ + soff;
            #pragma unroll 8
            for (int k = k0; k < k1; ++k, pp += PQ_) {
                uint32_t v = *pp;                 // coalesced stream (L3-resident)
                int idx = (int)(v & 0xFFFFu);
                float wv = (float)(v >> 16);
                float g = (idx < LDSN) ? ylds[idx] : yplane[idx];
                acc = fmaf(wv, g, acc);
            }
        } else {
            const int2*  ip = ind + (long long)k0 * PQ_ + soff;
            const float* wp = w1  + (long long)k0 * PQ_ + soff;
            #pragma unroll 4
            for (int k = k0; k < k1; ++k, ip += PQ_, wp += PQ_) {
                int2 ij = *ip;
                float wv = *wp;
                int idx = ij.x * QC + ij.y;
                float g = (idx < LDSN) ? ylds[idx] : yplane[idx];
                acc = fmaf(wv, g, acc);
            }
        }
        atomicAdd(&yout[(size_t)b * ostr + o], acc * ls);
    }
}

extern "C" void kernel_launch(void* const* d_in, const int* in_sizes, int n_in,
                              void* d_out, int out_size, void* d_ws, size_t ws_size,
                              hipStream_t stream)
{
    const float* inp = (const float*)d_in[0];
    const int2*  ind = (const int2*)d_in[1];
    const float* w1  = (const float*)d_in[2];
    const float* lam = (const float*)d_in[3];
    float* out = (float*)d_out;

    size_t packed_bytes = (((size_t)TOT * 4) + 255) & ~(size_t)255;
    size_t ybytes = (size_t)(2 * YSTR) * sizeof(float);   // two planes
    bool use_packed = ws_size >= packed_bytes + 2 * ybytes;

    uint8_t* ws = (uint8_t*)d_ws;
    uint32_t* packed = nullptr;
    float *y0, *y1;
    if (use_packed) {
        packed = (uint32_t*)ws;
        y0 = (float*)(ws + packed_bytes);
        y1 = (float*)(ws + packed_bytes + ybytes);
    } else {
        y0 = (float*)ws;
        y1 = (float*)(ws + ybytes);
    }

    if (use_packed) {
        unsigned nb = (unsigned)((TOT + 255) / 256);
        pack_kernel<<<dim3(nb), 256, 0, stream>>>(ind, w1, packed);
    }
    copy_kernel<<<(CPQ + 255) / 256, 256, 0, stream>>>(inp, y0);

    const int KS_C = 12, KS_F = 4;
    dim3 gC(128, 1, 2), gF(128, 1, 2);

    float* yin = y0; float* yout = y1;
    for (int it = 0; it < 4; ++it) {
        hipMemsetAsync(yout, 0, ybytes, stream);
        if (use_packed)
            iter_lds<false, true><<<gC, 1024, 0, stream>>>(packed, nullptr, nullptr, yin, yout, lam, KS_C);
        else
            iter_lds<false, false><<<gC, 1024, 0, stream>>>(nullptr, ind, w1, yin, yout, lam, KS_C);
        float* t = yin; yin = yout; yout = t;
    }
    hipMemsetAsync(out, 0, (size_t)PQ_ * 2 * sizeof(float), stream);
    if (use_packed)
        iter_lds<true, true><<<gF, 1024, 0, stream>>>(packed, nullptr, nullptr, yin, out, lam, KS_F);
    else
        iter_lds<true, false><<<gF, 1024, 0, stream>>>(nullptr, ind, w1, yin, out, lam, KS_F);
}